// Round 1
// baseline (61.882 us; speedup 1.0000x reference)
//
#include <hip/hip_runtime.h>

// Problem: B=4096 tokens, NB=16 branches, S=256 hidden, D=1024 model dim.
// out = x + ( relu(x) @ W_in[y]^T + b_in[y] ) @ W_out[y]^T + b_out[y]
// Grouped-GEMM formulation: only the selected branch per token is computed.

typedef unsigned short u16;
typedef short bf16x8 __attribute__((ext_vector_type(8)));
typedef float f32x4 __attribute__((ext_vector_type(4)));

#define MFMA16 __builtin_amdgcn_mfma_f32_16x16x32_bf16

constexpr int B_TOK = 4096;
constexpr int NB = 16;
constexpr int S_DIM = 256;
constexpr int D_DIM = 1024;
constexpr int BM = 64;                 // row tile
constexpr int PAD_ROWS = B_TOK + NB * BM;   // 5120 worst-case padded rows
constexpr int NTILES = PAD_ROWS / BM;       // 80 row tiles

__device__ __forceinline__ unsigned short f2bf(float f) {
    unsigned u = __builtin_bit_cast(unsigned, f);
    u += 0x7fffu + ((u >> 16) & 1u);   // round-to-nearest-even
    return (unsigned short)(u >> 16);
}
__device__ __forceinline__ unsigned pack2(float a, float b) {
    return (unsigned)f2bf(a) | ((unsigned)f2bf(b) << 16);
}

__device__ __forceinline__ void gload_lds16(const void* g, void* l) {
    __builtin_amdgcn_global_load_lds(
        (const __attribute__((address_space(1))) void*)g,
        (__attribute__((address_space(3))) void*)l, 16, 0, 0);
}

// ---------------------------------------------------------------------------
// Setup: histogram + aligned segment offsets + scatter permutation + tile map.
// Single block, 256 threads. Order within a branch is non-deterministic but the
// final output is order-invariant (each token's row is computed independently).
// ---------------------------------------------------------------------------
__global__ __launch_bounds__(256) void setup_kernel(
    const int* __restrict__ y, int* __restrict__ perm, int* __restrict__ tileBranch) {
    __shared__ int hist[NB];
    __shared__ int aoff[NB + 1];
    __shared__ int cursor[NB];
    const int t = threadIdx.x;
    if (t < NB) hist[t] = 0;
    __syncthreads();
    for (int i = t; i < B_TOK; i += 256) atomicAdd(&hist[y[i]], 1);
    __syncthreads();
    if (t == 0) {
        int off = 0;
        for (int n = 0; n < NB; ++n) {
            aoff[n] = off;
            cursor[n] = off;
            off += ((hist[n] + BM - 1) / BM) * BM;
        }
        aoff[NB] = off;
    }
    __syncthreads();
    for (int i = t; i < NTILES; i += 256) {
        int rb = i * BM, br = -1;
        for (int n = 0; n < NB; ++n)
            if (rb >= aoff[n] && rb < aoff[n + 1]) br = n;
        tileBranch[i] = br;
    }
    for (int i = t; i < PAD_ROWS; i += 256) perm[i] = -1;
    __syncthreads();
    for (int i = t; i < B_TOK; i += 256) {
        int n = y[i];
        int pos = atomicAdd(&cursor[n], 1);
        perm[pos] = i;
    }
}

// ---------------------------------------------------------------------------
// fp32 -> bf16 weight cast, 8 elems/thread, fully vectorized.
// ---------------------------------------------------------------------------
__global__ __launch_bounds__(256) void cast_w(
    const float* __restrict__ src, u16* __restrict__ dst, int n8) {
    int i = blockIdx.x * 256 + threadIdx.x;
    if (i >= n8) return;
    const float4* p = (const float4*)src + (size_t)i * 2;
    float4 v0 = p[0], v1 = p[1];
    uint4 o;
    o.x = pack2(v0.x, v0.y);
    o.y = pack2(v0.z, v0.w);
    o.z = pack2(v1.x, v1.y);
    o.w = pack2(v1.z, v1.w);
    ((uint4*)dst)[i] = o;
}

// ---------------------------------------------------------------------------
// Xp[row] = bf16(relu(x[perm[row]])) for valid rows, zeros for pad rows.
// ---------------------------------------------------------------------------
__global__ __launch_bounds__(256) void cast_x(
    const float* __restrict__ x, const int* __restrict__ perm, u16* __restrict__ Xp) {
    int tid = blockIdx.x * 256 + threadIdx.x;      // PAD_ROWS * (D/8) threads
    int row = tid >> 7;                            // 128 threads per row
    int c8 = (tid & 127) << 3;
    int tok = perm[row];
    uint4 o;
    if (tok >= 0) {
        const float4* p = (const float4*)&x[(size_t)tok * D_DIM + c8];
        float4 v0 = p[0], v1 = p[1];
        o.x = pack2(fmaxf(v0.x, 0.f), fmaxf(v0.y, 0.f));
        o.y = pack2(fmaxf(v0.z, 0.f), fmaxf(v0.w, 0.f));
        o.z = pack2(fmaxf(v1.x, 0.f), fmaxf(v1.y, 0.f));
        o.w = pack2(fmaxf(v1.z, 0.f), fmaxf(v1.w, 0.f));
    } else {
        o = make_uint4(0, 0, 0, 0);
    }
    *(uint4*)&Xp[(size_t)row * D_DIM + c8] = o;
}

// ---------------------------------------------------------------------------
// Grouped bf16 GEMM, NT layout (both A and B are K-contiguous row-major).
// C[r][c] = sum_k A[r][k] * Bw[branch][c][k]  (+ bias[branch][c])
// Tile 64x64, BK=64, 256 threads = 4 waves in 2x2, each wave 32x32 via
// 2x2 fragments of mfma_f32_16x16x32_bf16. global_load_lds width-16 staging.
// FINAL=false: store bf16 hid to HpOut.  FINAL=true: out[tok] = x[tok] + C.
// ---------------------------------------------------------------------------
template <bool FINAL>
__global__ __launch_bounds__(256) void gemm_tile(
    const u16* __restrict__ A, int lda,
    const u16* __restrict__ Bw,          // [NB][N][K] bf16
    const float* __restrict__ bias,      // [NB][N]
    const int* __restrict__ tileBranch,
    const int* __restrict__ perm,
    const float* __restrict__ xres,      // FINAL only
    u16* __restrict__ HpOut,             // !FINAL only
    float* __restrict__ out,             // FINAL only
    int K, int N) {
    const int branch = tileBranch[blockIdx.y];
    if (branch < 0) return;
    const int rowBase = blockIdx.y * BM;
    const int colBase = blockIdx.x * 64;

    __shared__ u16 sA[64 * 64];
    __shared__ u16 sB[64 * 64];

    const int t = threadIdx.x;
    const int srow = t >> 3;            // staging row 0..31
    const int scolB = (t & 7) << 4;     // staging byte col 0..112

    const u16* Bb = Bw + (size_t)branch * N * K + (size_t)colBase * K;

    const int lane = t & 63;
    const int wm = ((t >> 7) & 1) * 32; // wave row offset
    const int wn = ((t >> 6) & 1) * 32; // wave col offset
    const int fr = lane & 15;
    const int kc = (lane >> 4) * 8;

    f32x4 acc[2][2] = {};

    const int nK = K >> 6;
    for (int kt = 0; kt < nK; ++kt) {
        const int k0 = kt << 6;
        // stage A tile (64 rows x 64 cols bf16 = 8 KB): 2 x 4 KB waves-worth
#pragma unroll
        for (int i = 0; i < 2; ++i) {
            const char* g = (const char*)A +
                (((size_t)(rowBase + srow + i * 32)) * lda + k0) * 2 + scolB;
            gload_lds16(g, &sA[(i * 32 + srow) * 64 + (scolB >> 1)]);
        }
#pragma unroll
        for (int i = 0; i < 2; ++i) {
            const char* g = (const char*)Bb +
                (((size_t)(srow + i * 32)) * K + k0) * 2 + scolB;
            gload_lds16(g, &sB[(i * 32 + srow) * 64 + (scolB >> 1)]);
        }
        __syncthreads();   // waits vmcnt(0): LDS staging complete
#pragma unroll
        for (int kk = 0; kk < 2; ++kk) {
            const int kcol = kc + kk * 32;
            bf16x8 a0 = *(const bf16x8*)&sA[(wm + fr) * 64 + kcol];
            bf16x8 a1 = *(const bf16x8*)&sA[(wm + 16 + fr) * 64 + kcol];
            bf16x8 b0 = *(const bf16x8*)&sB[(wn + fr) * 64 + kcol];
            bf16x8 b1 = *(const bf16x8*)&sB[(wn + 16 + fr) * 64 + kcol];
            acc[0][0] = MFMA16(a0, b0, acc[0][0], 0, 0, 0);
            acc[0][1] = MFMA16(a0, b1, acc[0][1], 0, 0, 0);
            acc[1][0] = MFMA16(a1, b0, acc[1][0], 0, 0, 0);
            acc[1][1] = MFMA16(a1, b1, acc[1][1], 0, 0, 0);
        }
        __syncthreads();   // all reads done before next stage overwrites
    }

    // epilogue: C/D frag mapping col = lane&15, row = (lane>>4)*4 + reg
    const int r0 = (lane >> 4) * 4;
#pragma unroll
    for (int m = 0; m < 2; ++m) {
        const int prow0 = rowBase + wm + m * 16 + r0;
#pragma unroll
        for (int n = 0; n < 2; ++n) {
            const int col = colBase + wn + n * 16 + fr;
            const float bv = bias[branch * N + col];
#pragma unroll
            for (int r = 0; r < 4; ++r) {
                const float v = acc[m][n][r] + bv;
                const int prow = prow0 + r;
                if constexpr (!FINAL) {
                    HpOut[(size_t)prow * N + col] = f2bf(v);
                } else {
                    const int tok = perm[prow];
                    if (tok >= 0) {
                        const size_t o = (size_t)tok * N + col;
                        out[o] = xres[o] + v;
                    }
                }
            }
        }
    }
}

// ---------------------------------------------------------------------------
// kernel_launch
// ---------------------------------------------------------------------------
extern "C" void kernel_launch(void* const* d_in, const int* in_sizes, int n_in,
                              void* d_out, int out_size, void* d_ws, size_t ws_size,
                              hipStream_t stream) {
    const float* x     = (const float*)d_in[0];
    const int*   y     = (const int*)d_in[1];
    const float* W_in  = (const float*)d_in[2];
    const float* b_in  = (const float*)d_in[3];
    const float* W_out = (const float*)d_in[4];
    const float* b_out = (const float*)d_in[5];
    float* out = (float*)d_out;

    // workspace layout (bytes), ~29.9 MB total
    char* ws = (char*)d_ws;
    u16* Wi = (u16*)(ws);                                  // 16*256*1024*2 = 8 MB
    u16* Wo = (u16*)(ws + 8388608);                        // 8 MB
    u16* Xp = (u16*)(ws + 16777216);                       // 5120*1024*2 = 10 MB
    u16* Hp = (u16*)(ws + 27262976);                       // 5120*256*2 = 2.5 MB
    int* perm = (int*)(ws + 29884416);                     // 5120*4
    int* tileBranch = (int*)(ws + 29904896);               // 80*4

    setup_kernel<<<1, 256, 0, stream>>>(y, perm, tileBranch);

    // W casts: 16*256*1024 = 4194304 elems each -> 524288 threads
    cast_w<<<2048, 256, 0, stream>>>(W_in, Wi, 4194304 / 8);
    cast_w<<<2048, 256, 0, stream>>>(W_out, Wo, 4194304 / 8);

    // Xp: PAD_ROWS * 1024 / 8 = 655360 threads
    cast_x<<<2560, 256, 0, stream>>>(x, perm, Xp);

    // GEMM1: hid[5120p, 256] = Xp[5120p,1024] @ W_in[n][256,1024]^T + b_in
    gemm_tile<false><<<dim3(S_DIM / 64, NTILES), 256, 0, stream>>>(
        Xp, D_DIM, Wi, b_in, tileBranch, perm,
        nullptr, Hp, nullptr, D_DIM, S_DIM);

    // GEMM2: out[tok, 1024] = x[tok] + Hp[5120p,256] @ W_out[n][1024,256]^T + b_out
    gemm_tile<true><<<dim3(D_DIM / 64, NTILES), 256, 0, stream>>>(
        Hp, S_DIM, Wo, b_out, tileBranch, perm,
        x, nullptr, out, S_DIM, D_DIM);
}

// Round 2
// 57.318 us; speedup vs baseline: 1.0796x; 1.0796x over previous
//
#include <hip/hip_runtime.h>

// B=4096 tokens, NB=16 branches, S=256 hidden, D=1024.
// out = x + ( relu(x) @ W_in[y]^T + b_in[y] ) @ W_out[y]^T + b_out[y]
// Grouped-GEMM: 3 kernels.
//  K1 prep:  block 0 = setup (hist/offsets/perm/tileBranch); blocks 1.. = cast both W to bf16
//  K2 gemm1: hid = relu(x[perm]) @ W_in^T + b_in   (A gathered+cast in staging, 64x128 tiles)
//  K3 gemm2: out[tok] = x[tok] + hid @ W_out^T + b_out  (64x128 tiles, residual scatter)
// LDS bank conflicts removed via st-style XOR swizzle: reg-staged A writes swizzled;
// global_load_lds tiles use linear LDS dest + pre-swizzled per-lane global source (m173).

typedef unsigned short u16;
typedef short bf16x8 __attribute__((ext_vector_type(8)));
typedef float f32x4 __attribute__((ext_vector_type(4)));

#define MFMA16 __builtin_amdgcn_mfma_f32_16x16x32_bf16

constexpr int B_TOK = 4096;
constexpr int NB = 16;
constexpr int S_DIM = 256;
constexpr int D_DIM = 1024;
constexpr int BM = 64;
constexpr int PAD_ROWS = B_TOK + NB * BM;   // 5120
constexpr int NTILES = PAD_ROWS / BM;       // 80

__device__ __forceinline__ unsigned short f2bf(float f) {
    unsigned u = __builtin_bit_cast(unsigned, f);
    u += 0x7fffu + ((u >> 16) & 1u);   // RNE
    return (unsigned short)(u >> 16);
}
__device__ __forceinline__ unsigned pack2(float a, float b) {
    return (unsigned)f2bf(a) | ((unsigned)f2bf(b) << 16);
}
__device__ __forceinline__ void gload_lds16(const void* g, void* l) {
    __builtin_amdgcn_global_load_lds(
        (const __attribute__((address_space(1))) void*)g,
        (__attribute__((address_space(3))) void*)l, 16, 0, 0);
}

// ---------------------------------------------------------------------------
// K1: setup (block 0) + W fp32->bf16 casts (blocks 1..4096)
// ---------------------------------------------------------------------------
__global__ __launch_bounds__(256) void prep_kernel(
    const float* __restrict__ Wi_f, const float* __restrict__ Wo_f,
    u16* __restrict__ Wi, u16* __restrict__ Wo,
    const int* __restrict__ y, int* __restrict__ perm, int* __restrict__ tileBranch) {
    const int t = threadIdx.x;
    if (blockIdx.x == 0) {
        __shared__ int hist[NB];
        __shared__ int aoff[NB + 1];
        __shared__ int cursor[NB];
        if (t < NB) hist[t] = 0;
        __syncthreads();
        for (int i = t; i < B_TOK; i += 256) atomicAdd(&hist[y[i]], 1);
        __syncthreads();
        if (t == 0) {
            int off = 0;
            for (int n = 0; n < NB; ++n) {
                aoff[n] = off;
                cursor[n] = off;
                off += ((hist[n] + BM - 1) / BM) * BM;
            }
            aoff[NB] = off;
        }
        __syncthreads();
        for (int i = t; i < NTILES; i += 256) {
            int rb = i * BM, br = -1;
            for (int n = 0; n < NB; ++n)
                if (rb >= aoff[n] && rb < aoff[n + 1]) br = n;
            tileBranch[i] = br;
        }
        for (int i = t; i < PAD_ROWS; i += 256) perm[i] = -1;
        __syncthreads();
        for (int i = t; i < B_TOK; i += 256) {
            int pos = atomicAdd(&cursor[y[i]], 1);
            perm[pos] = i;
        }
        return;
    }
    // cast: 2 x 4194304 elems, 8 per thread
    int i = (blockIdx.x - 1) * 256 + t;          // 0 .. 1048575
    const float* src;
    u16* dst;
    int j;
    if (i < 524288) { src = Wi_f; dst = Wi; j = i; }
    else            { src = Wo_f; dst = Wo; j = i - 524288; }
    const float4* p = (const float4*)src + (size_t)j * 2;
    float4 v0 = p[0], v1 = p[1];
    uint4 o;
    o.x = pack2(v0.x, v0.y);
    o.y = pack2(v0.z, v0.w);
    o.z = pack2(v1.x, v1.y);
    o.w = pack2(v1.z, v1.w);
    ((uint4*)dst)[j] = o;
}

// ---------------------------------------------------------------------------
// K2: GEMM1  Hp[5120p,256] = relu(x[perm]) @ W_in[br]^T + b_in   (bf16 out)
// tile 64x128, BK=64, 256 threads = 4 waves (2x2 of 32x64 wave-tiles)
// ---------------------------------------------------------------------------
__global__ __launch_bounds__(256) void gemm1_kernel(
    const float* __restrict__ x, const u16* __restrict__ Wi,
    const float* __restrict__ b_in, const int* __restrict__ tileBranch,
    const int* __restrict__ perm, u16* __restrict__ Hp) {
    const int branch = tileBranch[blockIdx.y];
    if (branch < 0) return;
    const int rowBase = blockIdx.y * BM;
    const int colBase = blockIdx.x * 128;

    __shared__ u16 sA[64 * 64];    // XOR-swizzled (unit ^= row&7)
    __shared__ u16 sB[128 * 64];   // XOR-swizzled via pre-swizzled source

    const int t = threadIdx.x;
    // A staging map: 4 threads/row, 16 floats each
    const int ar = t >> 2;
    const int acg = t & 3;                          // col group (16 floats)
    const int tok = perm[rowBase + ar];
    const float* aSrc = (tok >= 0) ? (x + (size_t)tok * D_DIM + acg * 16) : x;
    const int abyte0 = (ar * 128 + acg * 32) ^ ((ar & 7) << 4);
    const int abyte1 = (ar * 128 + acg * 32 + 16) ^ ((ar & 7) << 4);

    const u16* Bb = Wi + (size_t)branch * S_DIM * D_DIM + (size_t)colBase * D_DIM;

    const int lane = t & 63;
    const int wid = t >> 6;
    const int wm = (wid >> 1) * 32;
    const int wn = (wid & 1) * 64;
    const int fr = lane & 15;
    const int kc = (lane >> 4) << 3;

    f32x4 acc[2][4] = {};

    // prefetch A regs for kt=0
    float4 v0, v1, v2, v3;
    {
        const float4* p = (const float4*)aSrc;
        v0 = p[0]; v1 = p[1]; v2 = p[2]; v3 = p[3];
    }

    for (int kt = 0; kt < 16; ++kt) {
        const int k0 = kt << 6;
        // B: global_load_lds, linear LDS dest, pre-swizzled source
#pragma unroll
        for (int i = 0; i < 4; ++i) {
            const int L = i * 4096 + t * 16;
            const int row = L >> 7;
            const int sunit = ((L >> 4) & 7) ^ (row & 7);
            const char* g = (const char*)Bb + (size_t)row * (D_DIM * 2) + k0 * 2 + sunit * 16;
            gload_lds16(g, (char*)sB + L);
        }
        // A: convert current regs -> swizzled ds_write
        uint4 w0, w1;
        if (tok >= 0) {
            w0.x = pack2(fmaxf(v0.x, 0.f), fmaxf(v0.y, 0.f));
            w0.y = pack2(fmaxf(v0.z, 0.f), fmaxf(v0.w, 0.f));
            w0.z = pack2(fmaxf(v1.x, 0.f), fmaxf(v1.y, 0.f));
            w0.w = pack2(fmaxf(v1.z, 0.f), fmaxf(v1.w, 0.f));
            w1.x = pack2(fmaxf(v2.x, 0.f), fmaxf(v2.y, 0.f));
            w1.y = pack2(fmaxf(v2.z, 0.f), fmaxf(v2.w, 0.f));
            w1.z = pack2(fmaxf(v3.x, 0.f), fmaxf(v3.y, 0.f));
            w1.w = pack2(fmaxf(v3.z, 0.f), fmaxf(v3.w, 0.f));
        } else {
            w0 = make_uint4(0, 0, 0, 0);
            w1 = make_uint4(0, 0, 0, 0);
        }
        *(uint4*)((char*)sA + abyte0) = w0;
        *(uint4*)((char*)sA + abyte1) = w1;
        // issue next-iter A loads; latency hides under barrier + MFMA
        if (kt < 15) {
            const float4* p = (const float4*)(aSrc + (k0 + 64));
            v0 = p[0]; v1 = p[1]; v2 = p[2]; v3 = p[3];
        }
        __syncthreads();
#pragma unroll
        for (int kk = 0; kk < 2; ++kk) {
            const int kcol = kc + kk * 32;
            const int ra0 = wm + fr, ra1 = wm + 16 + fr;
            bf16x8 a0 = *(const bf16x8*)&sA[(ra0 * 64 + kcol) ^ ((ra0 & 7) << 3)];
            bf16x8 a1 = *(const bf16x8*)&sA[(ra1 * 64 + kcol) ^ ((ra1 & 7) << 3)];
            bf16x8 b[4];
#pragma unroll
            for (int n = 0; n < 4; ++n) {
                const int rb = wn + n * 16 + fr;
                b[n] = *(const bf16x8*)&sB[(rb * 64 + kcol) ^ ((rb & 7) << 3)];
            }
#pragma unroll
            for (int n = 0; n < 4; ++n) {
                acc[0][n] = MFMA16(a0, b[n], acc[0][n], 0, 0, 0);
                acc[1][n] = MFMA16(a1, b[n], acc[1][n], 0, 0, 0);
            }
        }
        __syncthreads();
    }

    const int r0 = (lane >> 4) * 4;
#pragma unroll
    for (int m = 0; m < 2; ++m) {
        const int prow0 = rowBase + wm + m * 16 + r0;
#pragma unroll
        for (int n = 0; n < 4; ++n) {
            const int col = colBase + wn + n * 16 + fr;
            const float bv = b_in[branch * S_DIM + col];
#pragma unroll
            for (int r = 0; r < 4; ++r)
                Hp[(size_t)(prow0 + r) * S_DIM + col] = f2bf(acc[m][n][r] + bv);
        }
    }
}

// ---------------------------------------------------------------------------
// K3: GEMM2  out[tok,1024] = x[tok] + Hp @ W_out[br]^T + b_out
// tile 64x128, K=256 (4 K-steps), 256 threads = 4 waves
// ---------------------------------------------------------------------------
__global__ __launch_bounds__(256) void gemm2_kernel(
    const u16* __restrict__ Hp, const u16* __restrict__ Wo,
    const float* __restrict__ b_out, const int* __restrict__ tileBranch,
    const int* __restrict__ perm, const float* __restrict__ x,
    float* __restrict__ out) {
    const int branch = tileBranch[blockIdx.y];
    if (branch < 0) return;
    const int rowBase = blockIdx.y * BM;
    const int colBase = blockIdx.x * 128;

    __shared__ u16 sA[64 * 64];
    __shared__ u16 sB[128 * 64];

    const int t = threadIdx.x;
    const u16* Ab = Hp + (size_t)rowBase * S_DIM;
    const u16* Bb = Wo + (size_t)branch * D_DIM * S_DIM + (size_t)colBase * S_DIM;

    const int lane = t & 63;
    const int wid = t >> 6;
    const int wm = (wid >> 1) * 32;
    const int wn = (wid & 1) * 64;
    const int fr = lane & 15;
    const int kc = (lane >> 4) << 3;

    f32x4 acc[2][4] = {};

    for (int kt = 0; kt < 4; ++kt) {
        const int k0 = kt << 6;
#pragma unroll
        for (int i = 0; i < 2; ++i) {
            const int L = i * 4096 + t * 16;
            const int row = L >> 7;
            const int sunit = ((L >> 4) & 7) ^ (row & 7);
            const char* g = (const char*)Ab + (size_t)row * (S_DIM * 2) + k0 * 2 + sunit * 16;
            gload_lds16(g, (char*)sA + L);
        }
#pragma unroll
        for (int i = 0; i < 4; ++i) {
            const int L = i * 4096 + t * 16;
            const int row = L >> 7;
            const int sunit = ((L >> 4) & 7) ^ (row & 7);
            const char* g = (const char*)Bb + (size_t)row * (S_DIM * 2) + k0 * 2 + sunit * 16;
            gload_lds16(g, (char*)sB + L);
        }
        __syncthreads();
#pragma unroll
        for (int kk = 0; kk < 2; ++kk) {
            const int kcol = kc + kk * 32;
            const int ra0 = wm + fr, ra1 = wm + 16 + fr;
            bf16x8 a0 = *(const bf16x8*)&sA[(ra0 * 64 + kcol) ^ ((ra0 & 7) << 3)];
            bf16x8 a1 = *(const bf16x8*)&sA[(ra1 * 64 + kcol) ^ ((ra1 & 7) << 3)];
            bf16x8 b[4];
#pragma unroll
            for (int n = 0; n < 4; ++n) {
                const int rb = wn + n * 16 + fr;
                b[n] = *(const bf16x8*)&sB[(rb * 64 + kcol) ^ ((rb & 7) << 3)];
            }
#pragma unroll
            for (int n = 0; n < 4; ++n) {
                acc[0][n] = MFMA16(a0, b[n], acc[0][n], 0, 0, 0);
                acc[1][n] = MFMA16(a1, b[n], acc[1][n], 0, 0, 0);
            }
        }
        __syncthreads();
    }

    const int r0 = (lane >> 4) * 4;
#pragma unroll
    for (int m = 0; m < 2; ++m) {
        const int prow0 = rowBase + wm + m * 16 + r0;
#pragma unroll
        for (int r = 0; r < 4; ++r) {
            const int tok = perm[prow0 + r];
            if (tok < 0) continue;
#pragma unroll
            for (int n = 0; n < 4; ++n) {
                const int col = colBase + wn + n * 16 + fr;
                const size_t o = (size_t)tok * D_DIM + col;
                out[o] = x[o] + acc[m][n][r] + b_out[branch * D_DIM + col];
            }
        }
    }
}

// ---------------------------------------------------------------------------
extern "C" void kernel_launch(void* const* d_in, const int* in_sizes, int n_in,
                              void* d_out, int out_size, void* d_ws, size_t ws_size,
                              hipStream_t stream) {
    const float* x     = (const float*)d_in[0];
    const int*   y     = (const int*)d_in[1];
    const float* W_in  = (const float*)d_in[2];
    const float* b_in  = (const float*)d_in[3];
    const float* W_out = (const float*)d_in[4];
    const float* b_out = (const float*)d_in[5];
    float* out = (float*)d_out;

    char* ws = (char*)d_ws;
    u16* Wi = (u16*)(ws);                       // 8 MB
    u16* Wo = (u16*)(ws + 8388608);             // 8 MB
    u16* Hp = (u16*)(ws + 16777216);            // 5120*256*2 = 2.5 MB
    int* perm = (int*)(ws + 19398656);          // 5120*4
    int* tileBranch = (int*)(ws + 19419136);    // 80*4

    prep_kernel<<<4097, 256, 0, stream>>>(W_in, W_out, Wi, Wo, y, perm, tileBranch);

    gemm1_kernel<<<dim3(S_DIM / 128, NTILES), 256, 0, stream>>>(
        x, Wi, b_in, tileBranch, perm, Hp);

    gemm2_kernel<<<dim3(D_DIM / 128, NTILES), 256, 0, stream>>>(
        Hp, Wo, b_out, tileBranch, perm, x, out);
}

// Round 4
// 55.237 us; speedup vs baseline: 1.1203x; 1.0377x over previous
//
#include <hip/hip_runtime.h>

// B=4096 tokens, NB=16 branches, S=256 hidden, D=1024.
// out = x + ( relu(x) @ W_in[y]^T + b_in[y] ) @ W_out[y]^T + b_out[y]
// Grouped-GEMM, 3 kernels:
//  K1 prep:  block 0 = setup (hist/offsets/perm/tileBranch); blocks 1.. = cast W -> bf16
//  K2 gemm1: hid = relu(x[perm]) @ W_in^T + b_in   (64x64 tiles, 2-phase dbuf)
//  K3 gemm2: out[tok] = x[tok] + hid @ W_out^T + b_out (64x128 tiles, 2-phase dbuf,
//            LDS-bounce coalesced epilogue)
// Publishing contract for global_load_lds: EXPLICIT `s_waitcnt vmcnt(0)` before the
// __syncthreads that publishes a staged buffer (T3/T4 recipe). Round-2 relied on the
// compiler emitting it implicitly across a back-edge -> race -> NaN.
// LDS bank conflicts: XOR swizzle; gload_lds tiles use linear LDS dest +
// pre-swizzled per-lane global source (m173); reg-staged A writes swizzled directly.

typedef unsigned short u16;
typedef short bf16x8 __attribute__((ext_vector_type(8)));
typedef float f32x4 __attribute__((ext_vector_type(4)));

#define MFMA16 __builtin_amdgcn_mfma_f32_16x16x32_bf16

constexpr int B_TOK = 4096;
constexpr int NB = 16;
constexpr int S_DIM = 256;
constexpr int D_DIM = 1024;
constexpr int BM = 64;
constexpr int PAD_ROWS = B_TOK + NB * BM;   // 5120
constexpr int NTILES = PAD_ROWS / BM;       // 80

__device__ __forceinline__ unsigned short f2bf(float f) {
    unsigned u = __builtin_bit_cast(unsigned, f);
    u += 0x7fffu + ((u >> 16) & 1u);   // RNE
    return (unsigned short)(u >> 16);
}
__device__ __forceinline__ unsigned pack2(float a, float b) {
    return (unsigned)f2bf(a) | ((unsigned)f2bf(b) << 16);
}
__device__ __forceinline__ void gload_lds16(const void* g, void* l) {
    __builtin_amdgcn_global_load_lds(
        (const __attribute__((address_space(1))) void*)g,
        (__attribute__((address_space(3))) void*)l, 16, 0, 0);
}
// Publish staged LDS: drain ALL outstanding vmem (incl. global_load_lds), then barrier.
__device__ __forceinline__ void publish() {
    asm volatile("s_waitcnt vmcnt(0)" ::: "memory");
    __syncthreads();
}

// ---------------------------------------------------------------------------
// K1: setup (block 0) + W fp32->bf16 casts (blocks 1..4096)
// ---------------------------------------------------------------------------
__global__ __launch_bounds__(256) void prep_kernel(
    const float* __restrict__ Wi_f, const float* __restrict__ Wo_f,
    u16* __restrict__ Wi, u16* __restrict__ Wo,
    const int* __restrict__ y, int* __restrict__ perm, int* __restrict__ tileBranch) {
    const int t = threadIdx.x;
    if (blockIdx.x == 0) {
        __shared__ int hist[NB];
        __shared__ int aoff[NB + 1];
        __shared__ int cursor[NB];
        if (t < NB) hist[t] = 0;
        __syncthreads();
        for (int i = t; i < B_TOK; i += 256) atomicAdd(&hist[y[i]], 1);
        __syncthreads();
        if (t == 0) {
            int off = 0;
            for (int n = 0; n < NB; ++n) {
                aoff[n] = off;
                cursor[n] = off;
                off += ((hist[n] + BM - 1) / BM) * BM;
            }
            aoff[NB] = off;
        }
        __syncthreads();
        for (int i = t; i < NTILES; i += 256) {
            int rb = i * BM, br = -1;
            for (int n = 0; n < NB; ++n)
                if (rb >= aoff[n] && rb < aoff[n + 1]) br = n;
            tileBranch[i] = br;
        }
        for (int i = t; i < PAD_ROWS; i += 256) perm[i] = -1;
        __syncthreads();
        for (int i = t; i < B_TOK; i += 256) {
            int pos = atomicAdd(&cursor[y[i]], 1);
            perm[pos] = i;
        }
        return;
    }
    int i = (blockIdx.x - 1) * 256 + t;          // 0 .. 1048575
    const float* src;
    u16* dst;
    int j;
    if (i < 524288) { src = Wi_f; dst = Wi; j = i; }
    else            { src = Wo_f; dst = Wo; j = i - 524288; }
    const float4* p = (const float4*)src + (size_t)j * 2;
    float4 v0 = p[0], v1 = p[1];
    uint4 o;
    o.x = pack2(v0.x, v0.y);
    o.y = pack2(v0.z, v0.w);
    o.z = pack2(v1.x, v1.y);
    o.w = pack2(v1.z, v1.w);
    ((uint4*)dst)[j] = o;
}

// ---------------------------------------------------------------------------
// K2: GEMM1  Hp[5120p,256] = relu(x[perm]) @ W_in[br]^T + b_in   (bf16 out)
// tile 64x64, BK=64, 16 K-steps, 256 thr = 4 waves (2x2 of 32x32 wave-tiles)
// 2-phase: {issue stage(t+1); compute(t); pack/ds_write A(t+1); vmcnt(0); barrier}
// ---------------------------------------------------------------------------
__global__ __launch_bounds__(256) void gemm1_kernel(
    const float* __restrict__ x, const u16* __restrict__ Wi,
    const float* __restrict__ b_in, const int* __restrict__ tileBranch,
    const int* __restrict__ perm, u16* __restrict__ Hp) {
    const int branch = tileBranch[blockIdx.y];
    if (branch < 0) return;
    const int rowBase = blockIdx.y * BM;
    const int colBase = blockIdx.x * 64;

    __shared__ u16 sA[2][64 * 64];   // 8 KB each, XOR-swizzled
    __shared__ u16 sB[2][64 * 64];   // 8 KB each, swizzled via pre-swizzled source

    const int t = threadIdx.x;
    // A staging map: 4 threads/row, 16 floats each
    const int ar = t >> 2;
    const int acg = t & 3;
    const int tok = perm[rowBase + ar];
    const float* aSrc = (tok >= 0) ? (x + (size_t)tok * D_DIM + acg * 16) : x;
    const int abyte0 = (ar * 128 + acg * 32) ^ ((ar & 7) << 4);
    const int abyte1 = abyte0 ^ 16;

    const u16* Bb = Wi + (size_t)branch * S_DIM * D_DIM + (size_t)colBase * D_DIM;

    const int lane = t & 63;
    const int wid = t >> 6;
    const int wm = (wid >> 1) * 32;
    const int wn = (wid & 1) * 32;
    const int fr = lane & 15;
    const int kc = (lane >> 4) << 3;

    f32x4 acc[2][2] = {};

    auto stageB = [&](int buf, int k0) {
#pragma unroll
        for (int i = 0; i < 2; ++i) {
            const int L = i * 4096 + t * 16;
            const int row = L >> 7;
            const int sunit = ((L >> 4) & 7) ^ (row & 7);
            gload_lds16((const char*)Bb + (size_t)row * (D_DIM * 2) + k0 * 2 + sunit * 16,
                        (char*)sB[buf] + L);
        }
    };
    auto packWriteA = [&](int buf, float4 v0, float4 v1, float4 v2, float4 v3) {
        uint4 w0, w1;
        if (tok >= 0) {
            w0.x = pack2(fmaxf(v0.x, 0.f), fmaxf(v0.y, 0.f));
            w0.y = pack2(fmaxf(v0.z, 0.f), fmaxf(v0.w, 0.f));
            w0.z = pack2(fmaxf(v1.x, 0.f), fmaxf(v1.y, 0.f));
            w0.w = pack2(fmaxf(v1.z, 0.f), fmaxf(v1.w, 0.f));
            w1.x = pack2(fmaxf(v2.x, 0.f), fmaxf(v2.y, 0.f));
            w1.y = pack2(fmaxf(v2.z, 0.f), fmaxf(v2.w, 0.f));
            w1.z = pack2(fmaxf(v3.x, 0.f), fmaxf(v3.y, 0.f));
            w1.w = pack2(fmaxf(v3.z, 0.f), fmaxf(v3.w, 0.f));
        } else {
            w0 = make_uint4(0, 0, 0, 0);
            w1 = make_uint4(0, 0, 0, 0);
        }
        *(uint4*)((char*)sA[buf] + abyte0) = w0;
        *(uint4*)((char*)sA[buf] + abyte1) = w1;
    };

    // prologue: tile 0 staged and published
    float4 v0, v1, v2, v3;
    {
        const float4* p = (const float4*)aSrc;
        v0 = p[0]; v1 = p[1]; v2 = p[2]; v3 = p[3];
    }
    stageB(0, 0);
    packWriteA(0, v0, v1, v2, v3);   // compiler waits the 4 reg loads here
    publish();

    for (int kt = 0; kt < 16; ++kt) {
        const int cur = kt & 1;
        if (kt < 15) {
            const int k0n = (kt + 1) << 6;
            stageB(cur ^ 1, k0n);
            const float4* p = (const float4*)(aSrc + k0n);
            v0 = p[0]; v1 = p[1]; v2 = p[2]; v3 = p[3];
        }
        // compute(kt): LDS reads + MFMA (compiler inserts lgkm waits)
#pragma unroll
        for (int kk = 0; kk < 2; ++kk) {
            const int kcol = kc + kk * 32;
            const int ra0 = wm + fr, ra1 = wm + 16 + fr;
            const int rb0 = wn + fr, rb1 = wn + 16 + fr;
            bf16x8 a0 = *(const bf16x8*)&sA[cur][(ra0 * 64 + kcol) ^ ((ra0 & 7) << 3)];
            bf16x8 a1 = *(const bf16x8*)&sA[cur][(ra1 * 64 + kcol) ^ ((ra1 & 7) << 3)];
            bf16x8 b0 = *(const bf16x8*)&sB[cur][(rb0 * 64 + kcol) ^ ((rb0 & 7) << 3)];
            bf16x8 b1 = *(const bf16x8*)&sB[cur][(rb1 * 64 + kcol) ^ ((rb1 & 7) << 3)];
            acc[0][0] = MFMA16(a0, b0, acc[0][0], 0, 0, 0);
            acc[0][1] = MFMA16(a0, b1, acc[0][1], 0, 0, 0);
            acc[1][0] = MFMA16(a1, b0, acc[1][0], 0, 0, 0);
            acc[1][1] = MFMA16(a1, b1, acc[1][1], 0, 0, 0);
        }
        if (kt < 15) packWriteA(cur ^ 1, v0, v1, v2, v3);
        publish();   // drains stage(kt+1) vmem + ds_writes, then barrier
    }

    const int r0 = (lane >> 4) * 4;
#pragma unroll
    for (int m = 0; m < 2; ++m) {
        const int prow0 = rowBase + wm + m * 16 + r0;
#pragma unroll
        for (int n = 0; n < 2; ++n) {
            const int col = colBase + wn + n * 16 + fr;
            const float bv = b_in[branch * S_DIM + col];
#pragma unroll
            for (int r = 0; r < 4; ++r)
                Hp[(size_t)(prow0 + r) * S_DIM + col] = f2bf(acc[m][n][r] + bv);
        }
    }
}

// ---------------------------------------------------------------------------
// K3: GEMM2  out[tok,1024] = x[tok] + Hp @ W_out[br]^T + b_out
// tile 64x128, K=256 (4 K-steps), 2-phase dbuf, LDS-bounce coalesced epilogue
// ---------------------------------------------------------------------------
__global__ __launch_bounds__(256) void gemm2_kernel(
    const u16* __restrict__ Hp, const u16* __restrict__ Wo,
    const float* __restrict__ b_out, const int* __restrict__ tileBranch,
    const int* __restrict__ perm, const float* __restrict__ x,
    float* __restrict__ out) {
    const int branch = tileBranch[blockIdx.y];
    if (branch < 0) return;
    const int rowBase = blockIdx.y * BM;
    const int colBase = blockIdx.x * 128;

    __shared__ __align__(16) char smem[49152];  // sA[2]8K | sB[2]16K ; bounce 33.8K overlay
    u16* sA0 = (u16*)smem;
    u16* sA1 = (u16*)(smem + 8192);
    u16* sB0 = (u16*)(smem + 16384);
    u16* sB1 = (u16*)(smem + 32768);

    const int t = threadIdx.x;
    const u16* Ab = Hp + (size_t)rowBase * S_DIM;
    const u16* Bb = Wo + (size_t)branch * D_DIM * S_DIM + (size_t)colBase * S_DIM;

    const int lane = t & 63;
    const int wid = t >> 6;
    const int wm = (wid >> 1) * 32;
    const int wn = (wid & 1) * 64;
    const int fr = lane & 15;
    const int kc = (lane >> 4) << 3;

    f32x4 acc[2][4] = {};

    auto stage = [&](u16* dA, u16* dB, int k0) {
#pragma unroll
        for (int i = 0; i < 2; ++i) {
            const int L = i * 4096 + t * 16;
            const int row = L >> 7;
            const int sunit = ((L >> 4) & 7) ^ (row & 7);
            gload_lds16((const char*)Ab + (size_t)row * (S_DIM * 2) + k0 * 2 + sunit * 16,
                        (char*)dA + L);
        }
#pragma unroll
        for (int i = 0; i < 4; ++i) {
            const int L = i * 4096 + t * 16;
            const int row = L >> 7;
            const int sunit = ((L >> 4) & 7) ^ (row & 7);
            gload_lds16((const char*)Bb + (size_t)row * (S_DIM * 2) + k0 * 2 + sunit * 16,
                        (char*)dB + L);
        }
    };
    auto compute = [&](const u16* cA, const u16* cB) {
#pragma unroll
        for (int kk = 0; kk < 2; ++kk) {
            const int kcol = kc + kk * 32;
            const int ra0 = wm + fr, ra1 = wm + 16 + fr;
            bf16x8 a0 = *(const bf16x8*)&cA[(ra0 * 64 + kcol) ^ ((ra0 & 7) << 3)];
            bf16x8 a1 = *(const bf16x8*)&cA[(ra1 * 64 + kcol) ^ ((ra1 & 7) << 3)];
            bf16x8 b[4];
#pragma unroll
            for (int n = 0; n < 4; ++n) {
                const int rb = wn + n * 16 + fr;
                b[n] = *(const bf16x8*)&cB[(rb * 64 + kcol) ^ ((rb & 7) << 3)];
            }
#pragma unroll
            for (int n = 0; n < 4; ++n) {
                acc[0][n] = MFMA16(a0, b[n], acc[0][n], 0, 0, 0);
                acc[1][n] = MFMA16(a1, b[n], acc[1][n], 0, 0, 0);
            }
        }
    };

    stage(sA0, sB0, 0);
    publish();
#pragma unroll
    for (int kt = 0; kt < 4; ++kt) {
        const bool even = (kt & 1) == 0;
        if (kt < 3) stage(even ? sA1 : sA0, even ? sB1 : sB0, (kt + 1) << 6);
        compute(even ? sA0 : sA1, even ? sB0 : sB1);
        publish();   // drains next-tile stage (had the whole MFMA phase to land)
    }

    // ---- LDS-bounce epilogue: acc -> smem[64][132] f32 -> coalesced stores
    float* bo = (float*)smem;                 // [64][132] padded
    const int r0 = (lane >> 4) * 4;
#pragma unroll
    for (int m = 0; m < 2; ++m)
#pragma unroll
        for (int n = 0; n < 4; ++n)
#pragma unroll
            for (int r = 0; r < 4; ++r)
                bo[(wm + m * 16 + r0 + r) * 132 + wn + n * 16 + fr] = acc[m][n][r];
    __syncthreads();

    const int brow = t >> 2;                  // 0..63
    const int q4 = (t & 3) * 4;               // f32 col base within 16-col group
    const int tok2 = perm[rowBase + brow];
    if (tok2 >= 0) {
        const size_t gbase = (size_t)tok2 * D_DIM + colBase;
        const float* xr = x + gbase;
        float* orow = out + gbase;
        const float* br = b_out + (size_t)branch * D_DIM + colBase;
#pragma unroll
        for (int j = 0; j < 8; ++j) {
            const int c = q4 + j * 16;        // 4 lanes cover 16 consecutive f32
            float4 xv = *(const float4*)&xr[c];
            float4 bv = *(const float4*)&br[c];
            float4 hv = *(const float4*)&bo[brow * 132 + c];
            float4 s;
            s.x = xv.x + bv.x + hv.x;
            s.y = xv.y + bv.y + hv.y;
            s.z = xv.z + bv.z + hv.z;
            s.w = xv.w + bv.w + hv.w;
            *(float4*)&orow[c] = s;
        }
    }
}

// ---------------------------------------------------------------------------
extern "C" void kernel_launch(void* const* d_in, const int* in_sizes, int n_in,
                              void* d_out, int out_size, void* d_ws, size_t ws_size,
                              hipStream_t stream) {
    const float* x     = (const float*)d_in[0];
    const int*   y     = (const int*)d_in[1];
    const float* W_in  = (const float*)d_in[2];
    const float* b_in  = (const float*)d_in[3];
    const float* W_out = (const float*)d_in[4];
    const float* b_out = (const float*)d_in[5];
    float* out = (float*)d_out;

    char* ws = (char*)d_ws;
    u16* Wi = (u16*)(ws);                       // 8 MB
    u16* Wo = (u16*)(ws + 8388608);             // 8 MB
    u16* Hp = (u16*)(ws + 16777216);            // 2.5 MB
    int* perm = (int*)(ws + 19398656);          // 5120*4
    int* tileBranch = (int*)(ws + 19419136);    // 80*4

    prep_kernel<<<4097, 256, 0, stream>>>(W_in, W_out, Wi, Wo, y, perm, tileBranch);

    gemm1_kernel<<<dim3(S_DIM / 64, NTILES), 256, 0, stream>>>(
        x, Wi, b_in, tileBranch, perm, Hp);

    gemm2_kernel<<<dim3(D_DIM / 128, NTILES), 256, 0, stream>>>(
        Hp, Wo, b_out, tileBranch, perm, x, out);
}